// Round 17
// baseline (1882.351 us; speedup 1.0000x reference)
//
#include <hip/hip_runtime.h>
#include <math.h>

#define BB 8
#define TT 256
#define UU 128      // U
#define U1 129      // U+1
#define VV 256
#define ND 384      // anti-diagonals d = t+u
#define WROW 264    // floats per diag row: {blk[u],lbl[u]} pairs u=0..128 + pad
#define NEGF (-1e30f)
#define PF 16       // diagonals per ring slot
#define NSTAGE (BB * TT * U1 / 16)   // 16512 staging blocks (4 rows/wave x 4 waves)

// fast logaddexp: inputs finite (sentinel -1e30, never inf/nan)
__device__ __forceinline__ float logaddexpf_(float a, float b) {
    float m = fmaxf(a, b);
    float d = fminf(a, b) - m;
    return m + __logf(1.0f + __expf(d));
}

// wave-wide shift-right-by-1 via DPP (VALU) — lane l gets lane l-1's value
__device__ __forceinline__ float wave_shr1(float x) {
    int r = __builtin_amdgcn_update_dpp(0, __float_as_int(x), 0x138, 0xf, 0xf, true);
    return __int_as_float(r);
}

template <int CTRL>
__device__ __forceinline__ float dppadd(float x) {
    int t = __builtin_amdgcn_update_dpp(0, __float_as_int(x), CTRL, 0xf, 0xf, true);
    return x + __int_as_float(t);
}

// full-wave sum via 6 DPP VALU adds; result broadcast from lane 63
__device__ __forceinline__ float wave_sum(float s) {
    s = dppadd<0x111>(s);   // row_shr:1
    s = dppadd<0x112>(s);   // row_shr:2
    s = dppadd<0x114>(s);   // row_shr:4
    s = dppadd<0x118>(s);   // row_shr:8
    s = dppadd<0x142>(s);   // row_bcast:15
    s = dppadd<0x143>(s);   // row_bcast:31 -> lane 63 = full sum
    return __int_as_float(__builtin_amdgcn_readlane(__float_as_int(s), 63));
}

__device__ __forceinline__ float readlane_f(float x, int l) {
    return __int_as_float(__builtin_amdgcn_readlane(__float_as_int(x), l));
}

typedef float f4 __attribute__((ext_vector_type(4)));

// one DP step (consumer wave). f4 fields: .x=blk[u0] .y=lbl[u0] .z=blk[u1]
// .w=lbl[u1] — all from diagonal d-1. bj = blk[128] of diagonal d-1.
__device__ __forceinline__ void dp_step(
    int d, int u0, bool lane0, const f4 wj, float bj,
    float& a0, float& a1, float& a2,
    int dstar, bool isg0, bool isg1, bool isg128, float& saved)
{
    float pm = wave_shr1(a1);           // alpha[u0-1] from lane-1
    float pl = wave_shr1(wj.w);         // lbl[u0-1] from lane-1

    int t0 = d - u0;
    float c1 = (t0 >= 1) ? (a0 + wj.x) : NEGF;
    float c2 = lane0 ? NEGF : (pm + pl);
    float n0 = ((unsigned)t0 <= (TT - 1)) ? logaddexpf_(c1, c2) : NEGF;

    int t1 = t0 - 1;
    float c1b = (t1 >= 1) ? (a1 + wj.z) : NEGF;
    float c2b = a0 + wj.y;
    float n1 = ((unsigned)t1 <= (TT - 1)) ? logaddexpf_(c1b, c2b) : NEGF;

    int t2 = d - 128;                   // uniform
    float c1c = (t2 >= 1) ? (a2 + bj) : NEGF;
    float c2c = a1 + wj.w;
    float n2 = ((unsigned)t2 <= (TT - 1)) ? logaddexpf_(c1c, c2c) : NEGF;

    if (d == dstar) {                   // uniform scalar branch, true once
        float s1 = isg1 ? n1 : (isg128 ? n2 : 0.0f);
        saved = isg0 ? n0 : s1;
    }
    a0 = n0; a1 = n1; a2 = n2;
}

// FUSED kernel: blocks [0, NSTAGE) = staging (k_logprobs verbatim, then
// release-count); blocks [NSTAGE, NSTAGE+BB) = DP (spin-acquire, then the
// R16 named-reg producer/consumer DP with a 3-slot ring). Rationale: R16
// measured the DP at 70us/pass with VALUBusy 13%-of-active-CU, insensitive
// to memory residency (reps 2-3 L2-warm, FETCH 1.3MB) and to 5 structural
// rewrites — consistent with the chip running near its DPM clock floor when
// 8/256 CUs are active. Fusing makes the DP start 0us after full-chip
// activity in the SAME dispatch, before DVFS can downclock. No deadlock:
// DP blocks only spin; staging blocks never wait.
__global__ __launch_bounds__(256) void k_fused(
    const float* __restrict__ acts, const int* __restrict__ labels,
    const int* __restrict__ act_lens, const int* __restrict__ label_lens,
    float* __restrict__ wsD, float* __restrict__ bD128,
    float* __restrict__ costs, unsigned* __restrict__ cnt)
{
    __shared__ __align__(16) float ring[3][PF * 256];   // 3 x 16KB
    __shared__ __align__(16) float ldsF[ND + 32];       // blk[128] per diag

    int tid = threadIdx.x;
    int wave = tid >> 6;
    int lane = tid & 63;

    if (blockIdx.x < NSTAGE) {
        // ---------------- staging role (k_logprobs, proven ~18us) ----------
        int qid = (blockIdx.x << 2) + wave;             // < 66048 exactly
        qid = __builtin_amdgcn_readfirstlane(qid);
        int wid0 = qid * 4;

        int b = wid0 / (TT * U1);                       // uniform (33024 % 4 == 0)
        int flen = act_lens[b];
        int glen = label_lens[b];

        int tt[4], uu[4]; bool keep[4]; f4 v[4];
        #pragma unroll
        for (int r = 0; r < 4; ++r) {                   // all acts loads first (MLP)
            int wid = wid0 + r;
            int rem = wid - b * (TT * U1);
            int t = rem / U1;
            int u = rem - t * U1;
            tt[r] = t; uu[r] = u;
            keep[r] = (t < flen) && (u <= glen);        // wave-uniform branch
            v[r] = (f4){0.f, 0.f, 0.f, 0.f};
            if (keep[r])
                v[r] = __builtin_nontemporal_load((const f4*)(acts + (size_t)wid * VV) + lane);
        }

        float labv[4];
        #pragma unroll
        for (int r = 0; r < 4; ++r) {
            labv[r] = 0.f;
            if (keep[r] && uu[r] < UU)
                labv[r] = acts[(size_t)(wid0 + r) * VV + labels[b * UU + uu[r]]];
        }

        float lse[4];
        #pragma unroll
        for (int r = 0; r < 4; ++r) {
            float s = __expf(v[r].x) + __expf(v[r].y) + __expf(v[r].z) + __expf(v[r].w);
            lse[r] = __logf(wave_sum(s));
        }

        float myblk = 0.f, mylbl = 0.f; int myd = 0, myu = 0; bool mykeep = false;
        #pragma unroll
        for (int r = 0; r < 4; ++r) {
            float bs = readlane_f(v[r].x, 0);           // BLANK logit (elem 0, lane 0)
            if (lane == r) {
                myblk = bs - lse[r];
                mylbl = labv[r] - lse[r];
                myd = tt[r] + uu[r]; myu = uu[r]; mykeep = keep[r];
            }
        }
        if (lane < 4 && mykeep) {
            float2 val = make_float2(myblk, mylbl);
            *(float2*)(wsD + (size_t)(b * ND + myd) * WROW + 2 * myu) = val;
            if (myu == UU) bD128[b * ND + myd] = myblk;
        }

        // release: stores visible device-wide, then count this block done
        __threadfence();
        __syncthreads();
        if (tid == 0)
            __hip_atomic_fetch_add(cnt, 1u, __ATOMIC_RELEASE, __HIP_MEMORY_SCOPE_AGENT);
        return;
    }

    // ---------------- DP role ----------------
    int b = blockIdx.x - NSTAGE;
    const float* Wd = wsD + (size_t)b * ND * WROW;
    const float* Bg = bD128 + b * ND;
    int flen = act_lens[b];
    int glen = label_lens[b];
    int dstar = flen - 1 + glen;        // in [191, 383]
    int pmax  = (dstar - 1) / PF;       // last phase index (>= 11 always)

    // acquire: wait until all staging blocks have released
    if (tid == 0) {
        while (__hip_atomic_load(cnt, __ATOMIC_ACQUIRE, __HIP_MEMORY_SCOPE_AGENT) < (unsigned)NSTAGE)
            __builtin_amdgcn_s_sleep(2);
    }
    __syncthreads();
    __threadfence();

    const int u0 = 2 * lane;
    const bool lane0  = (lane == 0);
    const bool isg0   = (u0 == glen);
    const bool isg1   = (u0 + 1 == glen);
    const bool isg128 = (lane == 63) && (glen == 128);
    const bool have   = isg0 | isg1 | isg128;

    if (wave == 0) {
        #pragma unroll
        for (int k = 0; k < 6; ++k)
            ldsF[k * 64 + lane] = Bg[k * 64 + lane];
    } else {
        // prologue: producers batch-fill slots 0,1 with diags 0..31 (named regs)
        const int base = (wave - 1) * 11;
        #define PROW(k) ((base + (k) > 31) ? 31 : base + (k))
        f4 pv0, pv1, pv2, pv3, pv4, pv5, pv6, pv7, pv8, pv9, pv10;
        pv0  = *(const f4*)(Wd + (size_t)PROW(0)  * WROW + 4 * lane);
        pv1  = *(const f4*)(Wd + (size_t)PROW(1)  * WROW + 4 * lane);
        pv2  = *(const f4*)(Wd + (size_t)PROW(2)  * WROW + 4 * lane);
        pv3  = *(const f4*)(Wd + (size_t)PROW(3)  * WROW + 4 * lane);
        pv4  = *(const f4*)(Wd + (size_t)PROW(4)  * WROW + 4 * lane);
        pv5  = *(const f4*)(Wd + (size_t)PROW(5)  * WROW + 4 * lane);
        pv6  = *(const f4*)(Wd + (size_t)PROW(6)  * WROW + 4 * lane);
        pv7  = *(const f4*)(Wd + (size_t)PROW(7)  * WROW + 4 * lane);
        pv8  = *(const f4*)(Wd + (size_t)PROW(8)  * WROW + 4 * lane);
        pv9  = *(const f4*)(Wd + (size_t)PROW(9)  * WROW + 4 * lane);
        pv10 = *(const f4*)(Wd + (size_t)PROW(10) * WROW + 4 * lane);
        __builtin_amdgcn_sched_barrier(0);
        #define PWRITE(k, v) *(f4*)&ring[PROW(k) >> 4][(PROW(k) & 15) * 256 + 4 * lane] = v
        PWRITE(0, pv0);  PWRITE(1, pv1);  PWRITE(2, pv2);  PWRITE(3, pv3);
        PWRITE(4, pv4);  PWRITE(5, pv5);  PWRITE(6, pv6);  PWRITE(7, pv7);
        PWRITE(8, pv8);  PWRITE(9, pv9);  PWRITE(10, pv10);
        #undef PWRITE
        #undef PROW
    }
    __syncthreads();

    float a0 = lane0 ? 0.0f : NEGF;     // u = 2*lane
    float a1 = NEGF;                    // u = 2*lane+1
    float a2 = NEGF;                    // u = 128 (lane 63 only meaningful)
    float saved = 0.0f;

    #pragma unroll 1
    for (int p = 0; p <= pmax; ++p) {
        int dbase = 1 + p * PF;
        if (wave == 0) {
            // consumer: hoist 16 LDS reads, then 16 DP steps
            const float* slot = ring[p % 3];
            float b128v = (lane < PF) ? ldsF[dbase - 1 + lane] : 0.f;
            f4 wreg[PF];
            #pragma unroll
            for (int j = 0; j < PF; ++j)
                wreg[j] = *(const f4*)(slot + j * 256 + 4 * lane);
            #pragma unroll
            for (int j = 0; j < PF; ++j) {
                float bj = readlane_f(b128v, j);
                dp_step(dbase + j, u0, lane0, wreg[j], bj, a0, a1, a2,
                        dstar, isg0, isg1, isg128, saved);
            }
        } else {
            // producers: batch-fill slot (p+2)%3 (diags fbase-1+j), named regs
            int fbase = dbase + 2 * PF;
            if (fbase <= dstar) {
                float* slot = ring[(p + 2) % 3];
                const int base = (wave - 1) * 6;
                #define SROW(k) ((base + (k) > 15) ? 15 : base + (k))
                #define SDIAG(k) (((fbase - 1 + SROW(k)) > ND - 1) ? ND - 1 : fbase - 1 + SROW(k))
                f4 pv0, pv1, pv2, pv3, pv4, pv5;
                pv0 = *(const f4*)(Wd + (size_t)SDIAG(0) * WROW + 4 * lane);
                pv1 = *(const f4*)(Wd + (size_t)SDIAG(1) * WROW + 4 * lane);
                pv2 = *(const f4*)(Wd + (size_t)SDIAG(2) * WROW + 4 * lane);
                pv3 = *(const f4*)(Wd + (size_t)SDIAG(3) * WROW + 4 * lane);
                pv4 = *(const f4*)(Wd + (size_t)SDIAG(4) * WROW + 4 * lane);
                pv5 = *(const f4*)(Wd + (size_t)SDIAG(5) * WROW + 4 * lane);
                __builtin_amdgcn_sched_barrier(0);
                *(f4*)&slot[SROW(0) * 256 + 4 * lane] = pv0;
                *(f4*)&slot[SROW(1) * 256 + 4 * lane] = pv1;
                *(f4*)&slot[SROW(2) * 256 + 4 * lane] = pv2;
                *(f4*)&slot[SROW(3) * 256 + 4 * lane] = pv3;
                *(f4*)&slot[SROW(4) * 256 + 4 * lane] = pv4;
                *(f4*)&slot[SROW(5) * 256 + 4 * lane] = pv5;
                #undef SROW
                #undef SDIAG
            }
        }
        __syncthreads();
    }

    if (wave == 0 && have) {
        float blkv = Wd[(size_t)dstar * WROW + 2 * glen];
        costs[b] = -(saved + blkv);
    }
}

__global__ void k_sum(const float* __restrict__ costs, float* __restrict__ out)
{
    if (threadIdx.x == 0 && blockIdx.x == 0) {
        float s = 0.0f;
        for (int i = 0; i < BB; ++i) s += costs[i];
        out[0] = s;
    }
}

extern "C" void kernel_launch(void* const* d_in, const int* in_sizes, int n_in,
                              void* d_out, int out_size, void* d_ws, size_t ws_size,
                              hipStream_t stream) {
    const float* acts      = (const float*)d_in[0];
    const int*   labels    = (const int*)d_in[1];
    const int*   act_lens  = (const int*)d_in[2];
    const int*   label_lens= (const int*)d_in[3];
    float* out = (float*)d_out;

    float*    wsD   = (float*)d_ws;                    // 8*384*264 floats = 3.24 MB
    float*    bD128 = wsD + (size_t)BB * ND * WROW;    // 8*384 floats
    float*    costs = (float*)d_ws + (8u << 20);       // 32 MB in
    unsigned* cnt   = (unsigned*)((char*)d_ws + (64u << 20));  // 64 MB in

    hipMemsetAsync(cnt, 0, 64, stream);                // graph-legal async memset

    k_fused<<<NSTAGE + BB, 256, 0, stream>>>(acts, labels, act_lens, label_lens,
                                             wsD, bD128, costs, cnt);
    k_sum<<<1, 64, 0, stream>>>(costs, out);
}

// Round 18
// 269.352 us; speedup vs baseline: 6.9885x; 6.9885x over previous
//
#include <hip/hip_runtime.h>
#include <math.h>

#define BB 8
#define TT 256
#define UU 128      // U
#define U1 129      // U+1
#define VV 256
#define ND 384      // anti-diagonals d = t+u
#define WROW 264    // floats per diag row: {blk[u],lbl[u]} pairs u=0..128 + pad
#define NEGF (-1e30f)
#define PF 32       // diagonals per ring slot (R18: 16->32, tests fixed-vs-variable phase cost)

// fast logaddexp: inputs finite (sentinel -1e30, never inf/nan)
__device__ __forceinline__ float logaddexpf_(float a, float b) {
    float m = fmaxf(a, b);
    float d = fminf(a, b) - m;
    return m + __logf(1.0f + __expf(d));
}

// wave-wide shift-right-by-1 via DPP (VALU) — lane l gets lane l-1's value
__device__ __forceinline__ float wave_shr1(float x) {
    int r = __builtin_amdgcn_update_dpp(0, __float_as_int(x), 0x138, 0xf, 0xf, true);
    return __int_as_float(r);
}

template <int CTRL>
__device__ __forceinline__ float dppadd(float x) {
    int t = __builtin_amdgcn_update_dpp(0, __float_as_int(x), CTRL, 0xf, 0xf, true);
    return x + __int_as_float(t);
}

// full-wave sum via 6 DPP VALU adds; result broadcast from lane 63
__device__ __forceinline__ float wave_sum(float s) {
    s = dppadd<0x111>(s);   // row_shr:1
    s = dppadd<0x112>(s);   // row_shr:2
    s = dppadd<0x114>(s);   // row_shr:4
    s = dppadd<0x118>(s);   // row_shr:8
    s = dppadd<0x142>(s);   // row_bcast:15
    s = dppadd<0x143>(s);   // row_bcast:31 -> lane 63 = full sum
    return __int_as_float(__builtin_amdgcn_readlane(__float_as_int(s), 63));
}

__device__ __forceinline__ float readlane_f(float x, int l) {
    return __int_as_float(__builtin_amdgcn_readlane(__float_as_int(x), l));
}

typedef float f4 __attribute__((ext_vector_type(4)));

// Kernel 1 (~18us measured): 4 rows per wave, dead rows skipped, no-max LSE,
// DPP reduce, parallel float2 epilogue; writes compact bD128[b][d] too.
__global__ __launch_bounds__(256) void k_logprobs(
    const float* __restrict__ acts, const int* __restrict__ labels,
    const int* __restrict__ act_lens, const int* __restrict__ label_lens,
    float* __restrict__ wsD, float* __restrict__ bD128)
{
    const int NQUAD = BB * TT * U1 / 4;                 // 66048
    int qid = (blockIdx.x << 2) + (threadIdx.x >> 6);
    if (qid >= NQUAD) return;
    qid = __builtin_amdgcn_readfirstlane(qid);
    int lane = threadIdx.x & 63;
    int wid0 = qid * 4;

    int b = wid0 / (TT * U1);                           // uniform (33024 % 4 == 0)
    int flen = act_lens[b];
    int glen = label_lens[b];

    int tt[4], uu[4]; bool keep[4]; f4 v[4];
    #pragma unroll
    for (int r = 0; r < 4; ++r) {                       // all acts loads first (MLP)
        int wid = wid0 + r;
        int rem = wid - b * (TT * U1);
        int t = rem / U1;
        int u = rem - t * U1;
        tt[r] = t; uu[r] = u;
        keep[r] = (t < flen) && (u <= glen);            // wave-uniform branch
        v[r] = (f4){0.f, 0.f, 0.f, 0.f};
        if (keep[r])
            v[r] = __builtin_nontemporal_load((const f4*)(acts + (size_t)wid * VV) + lane);
    }

    float labv[4];
    #pragma unroll
    for (int r = 0; r < 4; ++r) {                       // label gathers
        labv[r] = 0.f;
        if (keep[r] && uu[r] < UU)
            labv[r] = acts[(size_t)(wid0 + r) * VV + labels[b * UU + uu[r]]];
    }

    float lse[4];
    #pragma unroll
    for (int r = 0; r < 4; ++r) {
        float s = __expf(v[r].x) + __expf(v[r].y) + __expf(v[r].z) + __expf(v[r].w);
        lse[r] = __logf(wave_sum(s));
    }

    // parallel epilogue: lane r owns row r
    float myblk = 0.f, mylbl = 0.f; int myd = 0, myu = 0; bool mykeep = false;
    #pragma unroll
    for (int r = 0; r < 4; ++r) {
        float bs = readlane_f(v[r].x, 0);               // BLANK logit (elem 0, lane 0)
        if (lane == r) {
            myblk = bs - lse[r];
            mylbl = labv[r] - lse[r];                   // u==128: garbage -> row pad, unread
            myd = tt[r] + uu[r]; myu = uu[r]; mykeep = keep[r];
        }
    }
    if (lane < 4 && mykeep) {
        float2 val = make_float2(myblk, mylbl);
        *(float2*)(wsD + (size_t)(b * ND + myd) * WROW + 2 * myu) = val;
        if (myu == UU) bD128[b * ND + myd] = myblk;
    }
}

// one DP step (consumer wave). f4 fields: .x=blk[u0] .y=lbl[u0] .z=blk[u1]
// .w=lbl[u1] — all from diagonal d-1. bj = blk[128] of diagonal d-1.
__device__ __forceinline__ void dp_step(
    int d, int u0, bool lane0, const f4 wj, float bj,
    float& a0, float& a1, float& a2,
    int dstar, bool isg0, bool isg1, bool isg128, float& saved)
{
    float pm = wave_shr1(a1);           // alpha[u0-1] from lane-1
    float pl = wave_shr1(wj.w);         // lbl[u0-1] from lane-1

    int t0 = d - u0;
    float c1 = (t0 >= 1) ? (a0 + wj.x) : NEGF;
    float c2 = lane0 ? NEGF : (pm + pl);
    float n0 = ((unsigned)t0 <= (TT - 1)) ? logaddexpf_(c1, c2) : NEGF;

    int t1 = t0 - 1;
    float c1b = (t1 >= 1) ? (a1 + wj.z) : NEGF;
    float c2b = a0 + wj.y;
    float n1 = ((unsigned)t1 <= (TT - 1)) ? logaddexpf_(c1b, c2b) : NEGF;

    int t2 = d - 128;                   // uniform
    float c1c = (t2 >= 1) ? (a2 + bj) : NEGF;
    float c2c = a1 + wj.w;
    float n2 = ((unsigned)t2 <= (TT - 1)) ? logaddexpf_(c1c, c2c) : NEGF;

    if (d == dstar) {                   // uniform scalar branch, true once
        float s1 = isg1 ? n1 : (isg128 ? n2 : 0.0f);
        saved = isg0 ? n0 : s1;
    }
    a0 = n0; a1 = n1; a2 = n2;
}

// Kernel 2: R16 named-reg producer/consumer structure at PF=32 (3-slot ring,
// 96KB LDS). If the measured ~10k-cycle phase cost is FIXED overhead, halving
// the phase count halves k_dp (~70 -> ~35-40us); if it scales with steps, no
// change — either way the result discriminates.
__global__ __launch_bounds__(256, 1) void k_dp(
    const float* __restrict__ wsD, const float* __restrict__ bD128,
    const int* __restrict__ act_lens, const int* __restrict__ label_lens,
    float* __restrict__ costs)
{
    __shared__ __align__(16) float ring[3][PF * 256];   // 3 x 32KB = 96KB
    __shared__ __align__(16) float ldsF[ND + 32];       // blk[128] per diag

    int b = blockIdx.x;
    int tid = threadIdx.x;
    int wave = tid >> 6;
    int lane = tid & 63;
    const float* Wd = wsD + (size_t)b * ND * WROW;
    const float* Bg = bD128 + b * ND;
    int flen = act_lens[b];
    int glen = label_lens[b];
    int dstar = flen - 1 + glen;        // in [191, 383]
    int pmax  = (dstar - 1) / PF;       // last phase index

    const int u0 = 2 * lane;
    const bool lane0  = (lane == 0);
    const bool isg0   = (u0 == glen);
    const bool isg1   = (u0 + 1 == glen);
    const bool isg128 = (lane == 63) && (glen == 128);
    const bool have   = isg0 | isg1 | isg128;

    if (wave == 0) {
        #pragma unroll
        for (int k = 0; k < 6; ++k)
            ldsF[k * 64 + lane] = Bg[k * 64 + lane];
    } else {
        // prologue: fill slots 0,1 (diags 0..63), 11 rows per producer per slot,
        // named regs, one load-cluster -> one write-cluster per slot.
        const int base = (wave - 1) * 11;
        #define PROW(k) ((base + (k) > 31) ? 31 : base + (k))
        {
            f4 q0,q1,q2,q3,q4,q5,q6,q7,q8,q9,q10;
            q0  = *(const f4*)(Wd + (size_t)PROW(0)  * WROW + 4 * lane);
            q1  = *(const f4*)(Wd + (size_t)PROW(1)  * WROW + 4 * lane);
            q2  = *(const f4*)(Wd + (size_t)PROW(2)  * WROW + 4 * lane);
            q3  = *(const f4*)(Wd + (size_t)PROW(3)  * WROW + 4 * lane);
            q4  = *(const f4*)(Wd + (size_t)PROW(4)  * WROW + 4 * lane);
            q5  = *(const f4*)(Wd + (size_t)PROW(5)  * WROW + 4 * lane);
            q6  = *(const f4*)(Wd + (size_t)PROW(6)  * WROW + 4 * lane);
            q7  = *(const f4*)(Wd + (size_t)PROW(7)  * WROW + 4 * lane);
            q8  = *(const f4*)(Wd + (size_t)PROW(8)  * WROW + 4 * lane);
            q9  = *(const f4*)(Wd + (size_t)PROW(9)  * WROW + 4 * lane);
            q10 = *(const f4*)(Wd + (size_t)PROW(10) * WROW + 4 * lane);
            __builtin_amdgcn_sched_barrier(0);
            *(f4*)&ring[0][PROW(0)  * 256 + 4 * lane] = q0;
            *(f4*)&ring[0][PROW(1)  * 256 + 4 * lane] = q1;
            *(f4*)&ring[0][PROW(2)  * 256 + 4 * lane] = q2;
            *(f4*)&ring[0][PROW(3)  * 256 + 4 * lane] = q3;
            *(f4*)&ring[0][PROW(4)  * 256 + 4 * lane] = q4;
            *(f4*)&ring[0][PROW(5)  * 256 + 4 * lane] = q5;
            *(f4*)&ring[0][PROW(6)  * 256 + 4 * lane] = q6;
            *(f4*)&ring[0][PROW(7)  * 256 + 4 * lane] = q7;
            *(f4*)&ring[0][PROW(8)  * 256 + 4 * lane] = q8;
            *(f4*)&ring[0][PROW(9)  * 256 + 4 * lane] = q9;
            *(f4*)&ring[0][PROW(10) * 256 + 4 * lane] = q10;
        }
        {
            f4 q0,q1,q2,q3,q4,q5,q6,q7,q8,q9,q10;
            q0  = *(const f4*)(Wd + (size_t)(PROW(0)  + 32) * WROW + 4 * lane);
            q1  = *(const f4*)(Wd + (size_t)(PROW(1)  + 32) * WROW + 4 * lane);
            q2  = *(const f4*)(Wd + (size_t)(PROW(2)  + 32) * WROW + 4 * lane);
            q3  = *(const f4*)(Wd + (size_t)(PROW(3)  + 32) * WROW + 4 * lane);
            q4  = *(const f4*)(Wd + (size_t)(PROW(4)  + 32) * WROW + 4 * lane);
            q5  = *(const f4*)(Wd + (size_t)(PROW(5)  + 32) * WROW + 4 * lane);
            q6  = *(const f4*)(Wd + (size_t)(PROW(6)  + 32) * WROW + 4 * lane);
            q7  = *(const f4*)(Wd + (size_t)(PROW(7)  + 32) * WROW + 4 * lane);
            q8  = *(const f4*)(Wd + (size_t)(PROW(8)  + 32) * WROW + 4 * lane);
            q9  = *(const f4*)(Wd + (size_t)(PROW(9)  + 32) * WROW + 4 * lane);
            q10 = *(const f4*)(Wd + (size_t)(PROW(10) + 32) * WROW + 4 * lane);
            __builtin_amdgcn_sched_barrier(0);
            *(f4*)&ring[1][PROW(0)  * 256 + 4 * lane] = q0;
            *(f4*)&ring[1][PROW(1)  * 256 + 4 * lane] = q1;
            *(f4*)&ring[1][PROW(2)  * 256 + 4 * lane] = q2;
            *(f4*)&ring[1][PROW(3)  * 256 + 4 * lane] = q3;
            *(f4*)&ring[1][PROW(4)  * 256 + 4 * lane] = q4;
            *(f4*)&ring[1][PROW(5)  * 256 + 4 * lane] = q5;
            *(f4*)&ring[1][PROW(6)  * 256 + 4 * lane] = q6;
            *(f4*)&ring[1][PROW(7)  * 256 + 4 * lane] = q7;
            *(f4*)&ring[1][PROW(8)  * 256 + 4 * lane] = q8;
            *(f4*)&ring[1][PROW(9)  * 256 + 4 * lane] = q9;
            *(f4*)&ring[1][PROW(10) * 256 + 4 * lane] = q10;
        }
        #undef PROW
    }
    __syncthreads();

    float a0 = lane0 ? 0.0f : NEGF;     // u = 2*lane
    float a1 = NEGF;                    // u = 2*lane+1
    float a2 = NEGF;                    // u = 128 (lane 63 only meaningful)
    float saved = 0.0f;

    #pragma unroll 1
    for (int p = 0; p <= pmax; ++p) {
        int dbase = 1 + p * PF;
        if (wave == 0) {
            // consumer: hoist 32 LDS reads, then 32 DP steps
            const float* slot = ring[p % 3];
            float b128v = (lane < PF) ? ldsF[dbase - 1 + lane] : 0.f;
            f4 wreg[PF];
            #pragma unroll
            for (int j = 0; j < PF; ++j)
                wreg[j] = *(const f4*)(slot + j * 256 + 4 * lane);
            #pragma unroll
            for (int j = 0; j < PF; ++j) {
                float bj = readlane_f(b128v, j);
                dp_step(dbase + j, u0, lane0, wreg[j], bj, a0, a1, a2,
                        dstar, isg0, isg1, isg128, saved);
            }
        } else {
            // producers: batch-fill slot (p+2)%3 (diags fbase-1+j), named regs
            int fbase = dbase + 2 * PF;
            if (fbase <= dstar) {
                float* slot = ring[(p + 2) % 3];
                const int base = (wave - 1) * 11;
                #define SROW(k) ((base + (k) > 31) ? 31 : base + (k))
                #define SDIAG(k) (((fbase - 1 + SROW(k)) > ND - 1) ? ND - 1 : fbase - 1 + SROW(k))
                f4 q0,q1,q2,q3,q4,q5,q6,q7,q8,q9,q10;
                q0  = *(const f4*)(Wd + (size_t)SDIAG(0)  * WROW + 4 * lane);
                q1  = *(const f4*)(Wd + (size_t)SDIAG(1)  * WROW + 4 * lane);
                q2  = *(const f4*)(Wd + (size_t)SDIAG(2)  * WROW + 4 * lane);
                q3  = *(const f4*)(Wd + (size_t)SDIAG(3)  * WROW + 4 * lane);
                q4  = *(const f4*)(Wd + (size_t)SDIAG(4)  * WROW + 4 * lane);
                q5  = *(const f4*)(Wd + (size_t)SDIAG(5)  * WROW + 4 * lane);
                q6  = *(const f4*)(Wd + (size_t)SDIAG(6)  * WROW + 4 * lane);
                q7  = *(const f4*)(Wd + (size_t)SDIAG(7)  * WROW + 4 * lane);
                q8  = *(const f4*)(Wd + (size_t)SDIAG(8)  * WROW + 4 * lane);
                q9  = *(const f4*)(Wd + (size_t)SDIAG(9)  * WROW + 4 * lane);
                q10 = *(const f4*)(Wd + (size_t)SDIAG(10) * WROW + 4 * lane);
                __builtin_amdgcn_sched_barrier(0);
                *(f4*)&slot[SROW(0)  * 256 + 4 * lane] = q0;
                *(f4*)&slot[SROW(1)  * 256 + 4 * lane] = q1;
                *(f4*)&slot[SROW(2)  * 256 + 4 * lane] = q2;
                *(f4*)&slot[SROW(3)  * 256 + 4 * lane] = q3;
                *(f4*)&slot[SROW(4)  * 256 + 4 * lane] = q4;
                *(f4*)&slot[SROW(5)  * 256 + 4 * lane] = q5;
                *(f4*)&slot[SROW(6)  * 256 + 4 * lane] = q6;
                *(f4*)&slot[SROW(7)  * 256 + 4 * lane] = q7;
                *(f4*)&slot[SROW(8)  * 256 + 4 * lane] = q8;
                *(f4*)&slot[SROW(9)  * 256 + 4 * lane] = q9;
                *(f4*)&slot[SROW(10) * 256 + 4 * lane] = q10;
                #undef SROW
                #undef SDIAG
            }
        }
        __syncthreads();
    }

    if (wave == 0 && have) {
        float blkv = Wd[(size_t)dstar * WROW + 2 * glen];
        costs[b] = -(saved + blkv);
    }
}

// Diagnostic: spin exactly 384000 shader-clock cycles on 8 blocks (the DP's
// sparse-CU regime). rocprof dur_us of this kernel directly measures the
// effective shader frequency: 160us -> 2.4GHz; ~770us -> ~500MHz DPM floor.
__global__ __launch_bounds__(64) void k_clock(float* __restrict__ dump)
{
    long long start = clock64();
    long long now = start;
    while (now - start < 384000) now = clock64();
    if (threadIdx.x == 0) dump[blockIdx.x] = (float)(now - start);
}

__global__ void k_sum(const float* __restrict__ costs, float* __restrict__ out)
{
    if (threadIdx.x == 0 && blockIdx.x == 0) {
        float s = 0.0f;
        for (int i = 0; i < BB; ++i) s += costs[i];
        out[0] = s;
    }
}

extern "C" void kernel_launch(void* const* d_in, const int* in_sizes, int n_in,
                              void* d_out, int out_size, void* d_ws, size_t ws_size,
                              hipStream_t stream) {
    const float* acts      = (const float*)d_in[0];
    const int*   labels    = (const int*)d_in[1];
    const int*   act_lens  = (const int*)d_in[2];
    const int*   label_lens= (const int*)d_in[3];
    float* out = (float*)d_out;

    float* wsD   = (float*)d_ws;                       // 8*384*264 floats = 3.24 MB
    float* bD128 = wsD + (size_t)BB * ND * WROW;       // 8*384 floats
    float* costs = (float*)d_ws + (8u << 20);          // 32 MB in
    float* dump  = costs + 64;                         // clock spin sink (unread)

    const int NQUAD = BB * TT * U1 / 4;                // 66048 waves
    int blocks = NQUAD / 4;                            // 16512 (exact)

    k_logprobs<<<blocks, 256, 0, stream>>>(acts, labels, act_lens, label_lens, wsD, bD128);
    k_dp<<<BB, 256, 0, stream>>>(wsD, bD128, act_lens, label_lens, costs);
    k_clock<<<BB, 64, 0, stream>>>(dump);
    k_sum<<<1, 64, 0, stream>>>(costs, out);
}

// Round 19
// 54.627 us; speedup vs baseline: 34.4586x; 4.9308x over previous
//
#include <hip/hip_runtime.h>
#include <math.h>

#define BB 8
#define TT 256
#define UU 128      // U
#define U1 129      // U+1
#define VV 256
#define ND 384      // anti-diagonals d = t+u
#define WROW 264    // floats per diag row: {pb[u],pl[u]} pairs u=0..128 + pad
#define NEGF (-1e30f)
#define PF 16       // diagonals per ring slot
#define NLN2_9  6.238324625f    // 9*ln2 (per-step spurious gain from the *512)
#define NLN2_29 20.10126823f    // 29*ln2 (rescale offset: anchor -> 2^-29)
#define TWO_M29 1.862645149e-9f // 2^-29

// wave-wide shift-right-by-1 via DPP; lane0 reads 0 (= additive identity
// in linear space: the u=0 boundary guard is free)
__device__ __forceinline__ float wave_shr1(float x) {
    int r = __builtin_amdgcn_update_dpp(0, __float_as_int(x), 0x138, 0xf, 0xf, true);
    return __int_as_float(r);
}

template <int CTRL>
__device__ __forceinline__ float dppadd(float x) {
    int t = __builtin_amdgcn_update_dpp(0, __float_as_int(x), CTRL, 0xf, 0xf, true);
    return x + __int_as_float(t);
}

// full-wave sum via 6 DPP VALU adds; result broadcast from lane 63
__device__ __forceinline__ float wave_sum(float s) {
    s = dppadd<0x111>(s); s = dppadd<0x112>(s); s = dppadd<0x114>(s);
    s = dppadd<0x118>(s); s = dppadd<0x142>(s); s = dppadd<0x143>(s);
    return __int_as_float(__builtin_amdgcn_readlane(__float_as_int(s), 63));
}

__device__ __forceinline__ float readlane_f(float x, int l) {
    return __int_as_float(__builtin_amdgcn_readlane(__float_as_int(x), l));
}

typedef float f4 __attribute__((ext_vector_type(4)));

// Kernel 1: as before (4 rows/wave, dead-skip, no-max LSE, DPP reduce,
// parallel float2 epilogue) but stores LINEAR-space scaled probabilities:
//   pb = exp(blk)*512, pl = exp(lbl)*512   (512=2^9 ~ cancels e^-6.2 decay)
__global__ __launch_bounds__(256) void k_logprobs(
    const float* __restrict__ acts, const int* __restrict__ labels,
    const int* __restrict__ act_lens, const int* __restrict__ label_lens,
    float* __restrict__ wsD, float* __restrict__ bD128)
{
    const int NQUAD = BB * TT * U1 / 4;                 // 66048
    int qid = (blockIdx.x << 2) + (threadIdx.x >> 6);
    if (qid >= NQUAD) return;
    qid = __builtin_amdgcn_readfirstlane(qid);
    int lane = threadIdx.x & 63;
    int wid0 = qid * 4;

    int b = wid0 / (TT * U1);                           // uniform (33024 % 4 == 0)
    int flen = act_lens[b];
    int glen = label_lens[b];

    int tt[4], uu[4]; bool keep[4]; f4 v[4];
    #pragma unroll
    for (int r = 0; r < 4; ++r) {
        int wid = wid0 + r;
        int rem = wid - b * (TT * U1);
        int t = rem / U1;
        int u = rem - t * U1;
        tt[r] = t; uu[r] = u;
        keep[r] = (t < flen) && (u <= glen);
        v[r] = (f4){0.f, 0.f, 0.f, 0.f};
        if (keep[r])
            v[r] = __builtin_nontemporal_load((const f4*)(acts + (size_t)wid * VV) + lane);
    }

    float labv[4];
    #pragma unroll
    for (int r = 0; r < 4; ++r) {
        labv[r] = 0.f;
        if (keep[r] && uu[r] < UU)
            labv[r] = acts[(size_t)(wid0 + r) * VV + labels[b * UU + uu[r]]];
    }

    float lse[4];
    #pragma unroll
    for (int r = 0; r < 4; ++r) {
        float s = __expf(v[r].x) + __expf(v[r].y) + __expf(v[r].z) + __expf(v[r].w);
        lse[r] = __logf(wave_sum(s));
    }

    float mypb = 0.f, mypl = 0.f; int myd = 0, myu = 0; bool mykeep = false;
    #pragma unroll
    for (int r = 0; r < 4; ++r) {
        float bs = readlane_f(v[r].x, 0);               // BLANK logit
        if (lane == r) {
            mypb = __expf(bs - lse[r]) * 512.f;
            mypl = __expf(labv[r] - lse[r]) * 512.f;    // u==128: garbage, pad, unread
            myd = tt[r] + uu[r]; myu = uu[r]; mykeep = keep[r];
        }
    }
    if (lane < 4 && mykeep) {
        float2 val = make_float2(mypb, mypl);
        *(float2*)(wsD + (size_t)(b * ND + myd) * WROW + 2 * myu) = val;
        if (myu == UU) bD128[b * ND + myd] = mypb;
    }
}

// Kernel 2: R16's verified producer/consumer skeleton; the DP step is now a
// LINEAR-space FMA chain (4-5 dependent ops vs ~25 with log-space): R18
// measured clock=2.374GHz (no DVFS) and ~23cy per dependent op on an idle CU
// -> chain length is the only lever. Per-phase band-centered rescale keeps
// floats in range; invalid cells stay exactly 0 (no guards needed).
__global__ __launch_bounds__(256, 1) void k_dp(
    const float* __restrict__ wsD, const float* __restrict__ bD128,
    const int* __restrict__ act_lens, const int* __restrict__ label_lens,
    float* __restrict__ costs)
{
    __shared__ __align__(16) float ring[4][PF * 256];   // 4 x 16KB
    __shared__ __align__(16) float ldsF[ND + 32];       // pb[128] per diag

    int b = blockIdx.x;
    int tid = threadIdx.x;
    int wave = tid >> 6;
    int lane = tid & 63;
    const float* Wd = wsD + (size_t)b * ND * WROW;
    const float* Bg = bD128 + b * ND;
    int flen = act_lens[b];
    int glen = label_lens[b];
    int dstar = flen - 1 + glen;        // in [191, 383]
    int pmax  = (dstar - 1) / PF;
    float invds = 1.0f / (float)dstar;

    const int u0 = 2 * lane;
    const bool lane0  = (lane == 0);
    const bool isg0   = (u0 == glen);
    const bool isg1   = (u0 + 1 == glen);
    const bool isg128 = (lane == 63) && (glen == 128);
    const bool have   = isg0 | isg1 | isg128;

    if (wave == 0) {
        #pragma unroll
        for (int k = 0; k < 6; ++k)
            ldsF[k * 64 + lane] = Bg[k * 64 + lane];
    } else {
        // prologue: batch-fill slots 0,1 with diags 0..31 (named regs)
        const int base = (wave - 1) * 11;
        #define PROW(k) ((base + (k) > 31) ? 31 : base + (k))
        f4 pv0, pv1, pv2, pv3, pv4, pv5, pv6, pv7, pv8, pv9, pv10;
        pv0  = *(const f4*)(Wd + (size_t)PROW(0)  * WROW + 4 * lane);
        pv1  = *(const f4*)(Wd + (size_t)PROW(1)  * WROW + 4 * lane);
        pv2  = *(const f4*)(Wd + (size_t)PROW(2)  * WROW + 4 * lane);
        pv3  = *(const f4*)(Wd + (size_t)PROW(3)  * WROW + 4 * lane);
        pv4  = *(const f4*)(Wd + (size_t)PROW(4)  * WROW + 4 * lane);
        pv5  = *(const f4*)(Wd + (size_t)PROW(5)  * WROW + 4 * lane);
        pv6  = *(const f4*)(Wd + (size_t)PROW(6)  * WROW + 4 * lane);
        pv7  = *(const f4*)(Wd + (size_t)PROW(7)  * WROW + 4 * lane);
        pv8  = *(const f4*)(Wd + (size_t)PROW(8)  * WROW + 4 * lane);
        pv9  = *(const f4*)(Wd + (size_t)PROW(9)  * WROW + 4 * lane);
        pv10 = *(const f4*)(Wd + (size_t)PROW(10) * WROW + 4 * lane);
        __builtin_amdgcn_sched_barrier(0);
        #define PWRITE(k, v) *(f4*)&ring[PROW(k) >> 4][(PROW(k) & 15) * 256 + 4 * lane] = v
        PWRITE(0, pv0);  PWRITE(1, pv1);  PWRITE(2, pv2);  PWRITE(3, pv3);
        PWRITE(4, pv4);  PWRITE(5, pv5);  PWRITE(6, pv6);  PWRITE(7, pv7);
        PWRITE(8, pv8);  PWRITE(9, pv9);  PWRITE(10, pv10);
        #undef PWRITE
        #undef PROW
    }
    __syncthreads();

    float a0 = lane0 ? 1.0f : 0.0f;     // A(u=2*lane), linear space
    float a1 = 0.0f;                    // A(u=2*lane+1)
    float a2 = 0.0f;                    // A(u=128), lane 63 only meaningful
    float ls = 0.0f;                    // rescale adjustments accumulator
    float saved = 0.0f;

    #pragma unroll 1
    for (int p = 0; p <= pmax; ++p) {
        int dbase = 1 + p * PF;
        if (wave == 0) {
            // band-centered rescale once per phase (anchor provably live;
            // anchor == target cell at d=dstar so 'saved' is well-scaled)
            if (p > 0) {
                int uc = (int)((float)(glen * (dbase - 1)) * invds);
                float s = readlane_f(a0, uc >> 1);
                float f = TWO_M29 / s;
                a0 *= f; a1 *= f; a2 *= f;
                ls += __logf(s) + NLN2_29;
            }
            const float* slot = ring[p & 3];
            float b128v = (lane < PF) ? ldsF[dbase - 1 + lane] : 0.f;
            f4 wreg[PF]; float plm[PF];
            #pragma unroll
            for (int j = 0; j < PF; ++j)
                wreg[j] = *(const f4*)(slot + j * 256 + 4 * lane);
            #pragma unroll
            for (int j = 0; j < PF; ++j)
                plm[j] = wave_shr1(wreg[j].w);          // pl[u0-1], off-chain
            #pragma unroll
            for (int j = 0; j < PF; ++j) {
                int d = dbase + j;
                float bj = readlane_f(b128v, j);
                float pm = wave_shr1(a1);               // A[u0-1] (0 at lane0)
                float n0 = fmaf(a0, wreg[j].x, pm * plm[j]);
                float n1 = fmaf(a1, wreg[j].z, a0 * wreg[j].y);
                float n2 = fmaf(a2, bj,        a1 * wreg[j].w);
                if (d == dstar) {                       // uniform, true once
                    float s1 = isg1 ? n1 : (isg128 ? n2 : 0.0f);
                    saved = isg0 ? n0 : s1;
                }
                a0 = n0; a1 = n1; a2 = n2;
            }
        } else {
            // producers: batch-fill slot (p+2)%4 (diags fbase-1+j), named regs
            int fbase = dbase + 2 * PF;
            if (fbase <= dstar) {
                float* slot = ring[(p + 2) & 3];
                const int base = (wave - 1) * 6;
                #define SROW(k) ((base + (k) > 15) ? 15 : base + (k))
                #define SDIAG(k) (((fbase - 1 + SROW(k)) > ND - 1) ? ND - 1 : fbase - 1 + SROW(k))
                f4 pv0, pv1, pv2, pv3, pv4, pv5;
                pv0 = *(const f4*)(Wd + (size_t)SDIAG(0) * WROW + 4 * lane);
                pv1 = *(const f4*)(Wd + (size_t)SDIAG(1) * WROW + 4 * lane);
                pv2 = *(const f4*)(Wd + (size_t)SDIAG(2) * WROW + 4 * lane);
                pv3 = *(const f4*)(Wd + (size_t)SDIAG(3) * WROW + 4 * lane);
                pv4 = *(const f4*)(Wd + (size_t)SDIAG(4) * WROW + 4 * lane);
                pv5 = *(const f4*)(Wd + (size_t)SDIAG(5) * WROW + 4 * lane);
                __builtin_amdgcn_sched_barrier(0);
                *(f4*)&slot[SROW(0) * 256 + 4 * lane] = pv0;
                *(f4*)&slot[SROW(1) * 256 + 4 * lane] = pv1;
                *(f4*)&slot[SROW(2) * 256 + 4 * lane] = pv2;
                *(f4*)&slot[SROW(3) * 256 + 4 * lane] = pv3;
                *(f4*)&slot[SROW(4) * 256 + 4 * lane] = pv4;
                *(f4*)&slot[SROW(5) * 256 + 4 * lane] = pv5;
                #undef SROW
                #undef SDIAG
            }
        }
        __syncthreads();
    }

    if (wave == 0 && have) {
        // true ll = log(saved) + ls - 9ln2*dstar + log(pb_fin/512)
        float pbF = Wd[(size_t)dstar * WROW + 2 * glen];   // 512*p_blank(final)
        float ll = __logf(saved) + ls - NLN2_9 * (float)dstar + __logf(pbF) - NLN2_9;
        costs[b] = -ll;
    }
}

__global__ void k_sum(const float* __restrict__ costs, float* __restrict__ out)
{
    if (threadIdx.x == 0 && blockIdx.x == 0) {
        float s = 0.0f;
        for (int i = 0; i < BB; ++i) s += costs[i];
        out[0] = s;
    }
}

extern "C" void kernel_launch(void* const* d_in, const int* in_sizes, int n_in,
                              void* d_out, int out_size, void* d_ws, size_t ws_size,
                              hipStream_t stream) {
    const float* acts      = (const float*)d_in[0];
    const int*   labels    = (const int*)d_in[1];
    const int*   act_lens  = (const int*)d_in[2];
    const int*   label_lens= (const int*)d_in[3];
    float* out = (float*)d_out;

    float* wsD   = (float*)d_ws;                       // 8*384*264 floats = 3.24 MB
    float* bD128 = wsD + (size_t)BB * ND * WROW;       // 8*384 floats
    float* costs = (float*)d_ws + (8u << 20);          // 32 MB in

    const int NQUAD = BB * TT * U1 / 4;                // 66048 waves
    int blocks = NQUAD / 4;                            // 16512 (exact)

    k_logprobs<<<blocks, 256, 0, stream>>>(acts, labels, act_lens, label_lens, wsD, bD128);
    k_dp<<<BB, 256, 0, stream>>>(wsD, bD128, act_lens, label_lens, costs);
    k_sum<<<1, 64, 0, stream>>>(costs, out);
}